// Round 16
// baseline (864.951 us; speedup 1.0000x reference)
//
#include <hip/hip_runtime.h>
#include <math.h>

// RWKV WKV forward — SINGLE-PASS decoupled-lookback chunked scan.
// Round-16: round-15 structure with the lookback TERMINATION BUG fixed:
// on consuming an aggregate from a j==0 predecessor (pb < B_), stop — its
// aggregate is its inclusive (exclusive prefix of chunk 0 = identity).
// Round-15 walked past it to g_flag[negative] -> hang/abort.
//
// Rationale (rounds 13/14): all passes run at clean cold-stream BW; y writes
// through to HBM regardless; so the only lever is reading k,v ONCE. Fused
// traffic ~340 MB vs 520 MB for the 3-pass -> predicted 75-95 us.

#define NEG_INF (-1e38f)
#define B_   8
#define T_   4096
#define C_   768
#define NCC  256
#define LL   16
#define NBLK (B_ * NCC)   // 2048
#define NTHR (C_ / 4)     // 192
#define C4_  (C_ / 4)

typedef float f4 __attribute__((ext_vector_type(4)));

// Published chunk summaries (fixed problem size -> static device arrays).
__device__ float g_agg_a[NBLK * C_];
__device__ float g_agg_b[NBLK * C_];
__device__ float g_agg_p[NBLK * C_];
__device__ float g_inc_a[NBLK * C_];
__device__ float g_inc_b[NBLK * C_];
__device__ float g_inc_p[NBLK * C_];
__device__ int   g_flag[NBLK];     // 0 = none, 1 = aggregate, 2 = inclusive
__device__ int   g_ticket;

__device__ __forceinline__ void wkv_step(float& aa, float& bb, float& pp,
                                         float wc, float kt, float vt) {
    float ww = wc + pp;
    float p  = fmaxf(ww, kt);
    float d  = ww - kt;
    float e  = __expf(-fabsf(d));
    float e1 = (d >= 0.f) ? 1.f : e;
    float e2 = (d >= 0.f) ? e   : 1.f;
    aa = e1 * aa + e2 * vt;
    bb = e1 * bb + e2;
    pp = p;
}

__device__ __forceinline__ float wkv_ostep(float aa, float bb, float pp,
                                           float uc, float kt, float vt) {
    float ww = uc + kt;
    float d  = pp - ww;
    float e  = __expf(-fabsf(d));
    float e1 = (d >= 0.f) ? 1.f : e;
    float e2 = (d >= 0.f) ? e   : 1.f;
    return __fdividef(e1 * aa + e2 * vt, e1 * bb + e2);
}

// A' = decay(A, dw) (+) S   (A,B,P modified in place; S spans the later steps)
__device__ __forceinline__ void wkv_combine(float& aa, float& bb, float& pp,
                                            float dw, float sa, float sb, float sp) {
    float ppd = pp + dw;
    float p   = fmaxf(ppd, sp);
    float e1  = __expf(ppd - p);
    float e2  = __expf(sp - p);
    aa = e1 * aa + e2 * sa;
    bb = e1 * bb + e2 * sb;
    pp = p;
}

// ---------------------------------------------------------------------------
__global__ void wkv_reset() {
    int i = blockIdx.x * blockDim.x + threadIdx.x;
    if (i < NBLK) g_flag[i] = 0;
    if (i == 0)   g_ticket = 0;
}

// ---------------------------------------------------------------------------
__global__ __launch_bounds__(NTHR, 2)
void wkv_fused(const float* __restrict__ w, const float* __restrict__ u,
               const float* __restrict__ kg, const float* __restrict__ vg,
               float* __restrict__ y) {
    __shared__ int s_t;
    __shared__ int s_f;
    const int tid = threadIdx.x;
    if (tid == 0) s_t = atomicAdd(&g_ticket, 1);
    __syncthreads();
    const int t = s_t;            // virtual block id: j = t>>3, b = t&7
    const int j = t >> 3;
    const int b = t & 7;

    const size_t rowbase = ((size_t)b * T_ + (size_t)j * LL) * C_;
    const f4* kp = (const f4*)(kg + rowbase) + tid;
    const f4* vp = (const f4*)(vg + rowbase) + tid;
    f4*       yp = (f4*)(y + rowbase) + tid;
    const f4  wc = ((const f4*)w)[tid];
    const f4  uc = ((const f4*)u)[tid];
    const int cbase = t * C_ + 4 * tid;

    // ---- load chunk once (nt: no L3 allocation, clean cold stream) ----
    f4 kb[LL], vb[LL];
    #pragma unroll
    for (int r = 0; r < LL; ++r) {
        kb[r] = __builtin_nontemporal_load(kp + r * C4_);
        vb[r] = __builtin_nontemporal_load(vp + r * C4_);
    }

    // ---- local summary ----
    float la[4] = {0.f, 0.f, 0.f, 0.f};
    float lb[4] = {0.f, 0.f, 0.f, 0.f};
    float lp[4] = {NEG_INF, NEG_INF, NEG_INF, NEG_INF};
    #pragma unroll
    for (int r = 0; r < LL; ++r) {
        #pragma unroll
        for (int q = 0; q < 4; ++q) {
            float kt = kb[r][q], vt = vb[r][q];
            wkv_step(la[q], lb[q], lp[q], wc[q], kt, vt);
        }
    }

    // ---- publish aggregate ----
    {
        f4 oa = {la[0], la[1], la[2], la[3]};
        f4 ob = {lb[0], lb[1], lb[2], lb[3]};
        f4 op = {lp[0], lp[1], lp[2], lp[3]};
        *(f4*)&g_agg_a[cbase] = oa;
        *(f4*)&g_agg_b[cbase] = ob;
        *(f4*)&g_agg_p[cbase] = op;
    }
    __threadfence();
    __syncthreads();
    if (tid == 0)
        __hip_atomic_store(&g_flag[t], 1, __ATOMIC_RELEASE, __HIP_MEMORY_SCOPE_AGENT);

    // ---- lookback: exclusive prefix (carry) for chunk j ----
    float ca[4] = {0.f, 0.f, 0.f, 0.f};
    float cb[4] = {0.f, 0.f, 0.f, 0.f};
    float cp[4] = {NEG_INF, NEG_INF, NEG_INF, NEG_INF};
    if (j > 0) {
        float ra[4] = {0.f, 0.f, 0.f, 0.f};          // suffix accumulator R
        float rb[4] = {0.f, 0.f, 0.f, 0.f};          // (m chunks before ours)
        float rp[4] = {NEG_INF, NEG_INF, NEG_INF, NEG_INF};
        int m = 0;
        int pb = t - B_;
        for (;;) {
            if (tid == 0)
                s_f = __hip_atomic_load(&g_flag[pb], __ATOMIC_ACQUIRE,
                                        __HIP_MEMORY_SCOPE_AGENT);
            __syncthreads();
            const int f = s_f;
            __syncthreads();
            if (f == 0) { __builtin_amdgcn_s_sleep(2); continue; }
            const int pc = pb * C_ + 4 * tid;
            const float dw = (float)(m * LL);
            if (f == 2) {
                // inclusive covers everything before R: carry = decay(incl) + R
                f4 xa = *(const f4*)&g_inc_a[pc];
                f4 xb = *(const f4*)&g_inc_b[pc];
                f4 xp = *(const f4*)&g_inc_p[pc];
                #pragma unroll
                for (int q = 0; q < 4; ++q) {
                    float A = xa[q], Bv = xb[q], P = xp[q];
                    wkv_combine(A, Bv, P, wc[q] * dw, ra[q], rb[q], rp[q]);
                    ca[q] = A; cb[q] = Bv; cp[q] = P;
                }
                break;
            }
            // f == 1: fold predecessor's aggregate into R
            {
                f4 xa = *(const f4*)&g_agg_a[pc];
                f4 xb = *(const f4*)&g_agg_b[pc];
                f4 xp = *(const f4*)&g_agg_p[pc];
                #pragma unroll
                for (int q = 0; q < 4; ++q) {
                    float A = xa[q], Bv = xb[q], P = xp[q];
                    wkv_combine(A, Bv, P, wc[q] * dw, ra[q], rb[q], rp[q]);
                    ra[q] = A; rb[q] = Bv; rp[q] = P;
                }
                m += 1;
            }
            if (pb < B_) {               // chunk 0 consumed: R is the full carry
                #pragma unroll
                for (int q = 0; q < 4; ++q) { ca[q] = ra[q]; cb[q] = rb[q]; cp[q] = rp[q]; }
                break;
            }
            pb -= B_;
        }
    }

    // ---- publish inclusive = decay(carry, LL) (+) own aggregate ----
    {
        float ia[4], ib[4], ip[4];
        #pragma unroll
        for (int q = 0; q < 4; ++q) {
            float A = ca[q], Bv = cb[q], P = cp[q];
            wkv_combine(A, Bv, P, wc[q] * (float)LL, la[q], lb[q], lp[q]);
            ia[q] = A; ib[q] = Bv; ip[q] = P;
        }
        f4 oa = {ia[0], ia[1], ia[2], ia[3]};
        f4 ob = {ib[0], ib[1], ib[2], ib[3]};
        f4 op = {ip[0], ip[1], ip[2], ip[3]};
        *(f4*)&g_inc_a[cbase] = oa;
        *(f4*)&g_inc_b[cbase] = ob;
        *(f4*)&g_inc_p[cbase] = op;
    }
    __threadfence();
    __syncthreads();
    if (tid == 0)
        __hip_atomic_store(&g_flag[t], 2, __ATOMIC_RELEASE, __HIP_MEMORY_SCOPE_AGENT);

    // ---- replay chunk from registers with carry state; emit y ----
    float aa[4], bb[4], pp[4];
    #pragma unroll
    for (int q = 0; q < 4; ++q) { aa[q] = ca[q]; bb[q] = cb[q]; pp[q] = cp[q]; }
    #pragma unroll
    for (int r = 0; r < LL; ++r) {
        f4 yo;
        #pragma unroll
        for (int q = 0; q < 4; ++q) {
            float kt = kb[r][q], vt = vb[r][q];
            yo[q] = wkv_ostep(aa[q], bb[q], pp[q], uc[q], kt, vt);
            wkv_step(aa[q], bb[q], pp[q], wc[q], kt, vt);
        }
        yp[r * C4_] = yo;
    }
}

// ---------------------------------------------------------------------------
extern "C" void kernel_launch(void* const* d_in, const int* in_sizes, int n_in,
                              void* d_out, int out_size, void* d_ws, size_t ws_size,
                              hipStream_t stream) {
    // inputs: 0=B 1=T 2=C 3=w 4=u 5=k 6=v  (fixed instance: 8/4096/768)
    const float* w = (const float*)d_in[3];
    const float* u = (const float*)d_in[4];
    const float* k = (const float*)d_in[5];
    const float* v = (const float*)d_in[6];
    float* y = (float*)d_out;

    wkv_reset<<<(NBLK + 255) / 256, 256, 0, stream>>>();
    wkv_fused<<<NBLK, NTHR, 0, stream>>>(w, u, k, v, y);
}

// Round 17
// 104.239 us; speedup vs baseline: 8.2977x; 8.2977x over previous
//
#include <hip/hip_runtime.h>
#include <math.h>

// RWKV WKV forward — chunked scan, NCC=256 chunks of LL=16, hierarchical prefix.
// FINAL (round-17): the measured-best structure (104.2 us, rounds 1/5/12).
//
// Complete characterization (rounds 0-16):
// - Traffic: k,v read twice (pass1 cold, pass3 L3-hot) + y write + states.
// - pass1 (~79 us): reads the ~98 MB of k,v evicted from L3 by y's writes each
//   replay (k+v 201 + y 100 + states 19 = 320 MB > 256 MB L3). Refilling
//   scattered holes runs at ~1.3 TB/s regardless of kernel shape — proven
//   invariant across 6 load structures AND a pure copy control (77-84 us).
// - nt-store: no-op for L3 allocation. nt-load: real (clean 48 us pass1) but
//   moves the cold read to pass3 (118 us total) — net worse.
// - Single-read fused lookback: correct (absmax 0.0078) and traffic-ideal
//   (301 MB) but serial inclusive chain = 255 hops x ~3.5 us = 865 us. Dead.
// - Roofline: 79 (pattern-floor cold read) + ~5 (scans) + ~20 (hot pass3 +
//   y-write floor) = 104 us. This source measures 104.2.

#define NEG_INF (-1e38f)
#define NCC 256          // chunks per sequence
#define SCW 16           // chunks per superchunk
#define NSC (NCC / SCW)  // superchunks = 16
#define LL  16           // timesteps per chunk (T=4096 / NCC)

typedef float f4 __attribute__((ext_vector_type(4)));

__device__ __forceinline__ void wkv_step(float& aa, float& bb, float& pp,
                                         float wc, float kt, float vt) {
    float ww = wc + pp;
    float p  = fmaxf(ww, kt);
    float d  = ww - kt;
    float e  = __expf(-fabsf(d));
    float e1 = (d >= 0.f) ? 1.f : e;
    float e2 = (d >= 0.f) ? e   : 1.f;
    aa = e1 * aa + e2 * vt;
    bb = e1 * bb + e2;
    pp = p;
}

__device__ __forceinline__ float wkv_ostep(float aa, float bb, float pp,
                                           float uc, float kt, float vt) {
    float ww = uc + kt;
    float d  = pp - ww;
    float e  = __expf(-fabsf(d));
    float e1 = (d >= 0.f) ? 1.f : e;
    float e2 = (d >= 0.f) ? e   : 1.f;
    return __fdividef(e1 * aa + e2 * vt, e1 * bb + e2);
}

// S = decay(S, dw) (+) (la, lb, lp)
__device__ __forceinline__ void wkv_combine(float& aa, float& bb, float& pp,
                                            float dw, float la, float lb, float lp) {
    float ppd = pp + dw;
    float p   = fmaxf(ppd, lp);
    float e1  = __expf(ppd - p);
    float e2  = __expf(lp - p);
    aa = e1 * aa + e2 * la;
    bb = e1 * bb + e2 * lb;
    pp = p;
}

// ---------------------------------------------------------------------------
// Pass 1: per-(b, chunk) local summary. One block per (b,j); C/4 threads,
// 4 adjacent channels each. Absorbs the cold-read phase.
__global__ __launch_bounds__(192)
void wkv_pass1(const float* __restrict__ w,
               const float* __restrict__ kg,
               const float* __restrict__ vg,
               float* __restrict__ sa, float* __restrict__ sb,
               float* __restrict__ sp,
               int B, int T, int C) {
    const int b   = blockIdx.x / NCC;
    const int j   = blockIdx.x % NCC;
    const int tid = threadIdx.x;
    const int C4  = C >> 2;

    const f4* kp = (const f4*)(kg + ((size_t)b * T + (size_t)j * LL) * C) + tid;
    const f4* vp = (const f4*)(vg + ((size_t)b * T + (size_t)j * LL) * C) + tid;
    const f4  wc = ((const f4*)w)[tid];

    f4 kb[LL], vb[LL];
    #pragma unroll
    for (int t = 0; t < LL; ++t) { kb[t] = kp[t * C4]; vb[t] = vp[t * C4]; }
    __builtin_amdgcn_sched_group_barrier(0x20, 2 * LL + 1, 0);

    float aa[4] = {0.f, 0.f, 0.f, 0.f};
    float bb[4] = {0.f, 0.f, 0.f, 0.f};
    float pp[4] = {NEG_INF, NEG_INF, NEG_INF, NEG_INF};
    #pragma unroll
    for (int t = 0; t < LL; ++t) {
        #pragma unroll
        for (int q = 0; q < 4; ++q) {
            float kt = kb[t][q], vt = vb[t][q];
            wkv_step(aa[q], bb[q], pp[q], wc[q], kt, vt);
        }
    }

    const int base = j * (B * C) + b * C;
    f4 oa = {aa[0], aa[1], aa[2], aa[3]};
    f4 ob = {bb[0], bb[1], bb[2], bb[3]};
    f4 op = {pp[0], pp[1], pp[2], pp[3]};
    ((f4*)(sa + base))[tid] = oa;
    ((f4*)(sb + base))[tid] = ob;
    ((f4*)(sp + base))[tid] = op;
}

// ---------------------------------------------------------------------------
// Scan 2a: inclusive scan of SCW chunk summaries inside each superchunk,
// in place. One thread per (channel, superchunk). Load-all-then-store.
__global__ void wkv_scan_local(const float* __restrict__ w,
                               float* __restrict__ sa, float* __restrict__ sb,
                               float* __restrict__ sp,
                               int B, int C) {
    const int BC = B * C;
    int tid = blockIdx.x * blockDim.x + threadIdx.x;
    if (tid >= BC * NSC) return;
    const int bc = tid % BC;
    const int sc = tid / BC;
    const float wL = w[bc % C] * (float)LL;

    float la[SCW], lb[SCW], lp[SCW];
    #pragma unroll
    for (int i = 0; i < SCW; ++i) {
        const int idx = (sc * SCW + i) * BC + bc;
        la[i] = sa[idx]; lb[i] = sb[idx]; lp[i] = sp[idx];
    }
    float aa = 0.f, bb = 0.f, pp = NEG_INF;
    #pragma unroll
    for (int i = 0; i < SCW; ++i) {
        wkv_combine(aa, bb, pp, wL, la[i], lb[i], lp[i]);
        const int idx = (sc * SCW + i) * BC + bc;
        sa[idx] = aa; sb[idx] = bb; sp[idx] = pp;
    }
}

// ---------------------------------------------------------------------------
// Scan 2b: exclusive scan over superchunk totals (in each superchunk's last
// chunk slot); overwrite those slots with the superchunk carry-in E_sc.
__global__ void wkv_scan_super(const float* __restrict__ w,
                               float* __restrict__ sa, float* __restrict__ sb,
                               float* __restrict__ sp,
                               int B, int C) {
    const int BC = B * C;
    int bc = blockIdx.x * blockDim.x + threadIdx.x;
    if (bc >= BC) return;
    const float wSL = w[bc % C] * (float)(LL * SCW);

    float ta[NSC], tb[NSC], tp[NSC];
    #pragma unroll
    for (int sc = 0; sc < NSC; ++sc) {
        const int idx = (sc * SCW + (SCW - 1)) * BC + bc;
        ta[sc] = sa[idx]; tb[sc] = sb[idx]; tp[sc] = sp[idx];
    }
    float aa = 0.f, bb = 0.f, pp = NEG_INF;
    #pragma unroll
    for (int sc = 0; sc < NSC; ++sc) {
        const int idx = (sc * SCW + (SCW - 1)) * BC + bc;
        sa[idx] = aa; sb[idx] = bb; sp[idx] = pp;       // E_sc (exclusive)
        wkv_combine(aa, bb, pp, wSL, ta[sc], tb[sc], tp[sc]);
    }
}

// ---------------------------------------------------------------------------
// Pass 3: carry-in for chunk j = decay(E_sc, i*LL*w) (+) incl(j-1); replay
// chunk from L3-hot k,v, emit y with 16-byte nt stores.
__global__ __launch_bounds__(192)
void wkv_pass3(const float* __restrict__ w, const float* __restrict__ u,
               const float* __restrict__ kg, const float* __restrict__ vg,
               const float* __restrict__ sa, const float* __restrict__ sb,
               const float* __restrict__ sp,
               float* __restrict__ y,
               int B, int T, int C) {
    const int b   = blockIdx.x / NCC;
    const int j   = blockIdx.x % NCC;
    const int tid = threadIdx.x;
    const int C4  = C >> 2;
    const int BC  = B * C;

    const size_t rowbase = ((size_t)b * T + (size_t)j * LL) * C;
    const f4* kp = (const f4*)(kg + rowbase) + tid;
    const f4* vp = (const f4*)(vg + rowbase) + tid;
    f4*       yp = (f4*)(y + rowbase) + tid;
    const f4  wc = ((const f4*)w)[tid];
    const f4  uc = ((const f4*)u)[tid];

    f4 kb[LL], vb[LL];
    #pragma unroll
    for (int t = 0; t < LL; ++t) { kb[t] = kp[t * C4]; vb[t] = vp[t * C4]; }
    __builtin_amdgcn_sched_group_barrier(0x20, 2 * LL, 0);

    const int sc = j / SCW;
    const int i  = j % SCW;
    const int slot_last = (sc * SCW + (SCW - 1)) * BC + b * C;
    f4 Ea = ((const f4*)(sa + slot_last))[tid];
    f4 Eb = ((const f4*)(sb + slot_last))[tid];
    f4 Ep = ((const f4*)(sp + slot_last))[tid];

    float aa[4], bb[4], pp[4];
    if (i == 0) {                       // block-uniform branch
        #pragma unroll
        for (int q = 0; q < 4; ++q) { aa[q] = Ea[q]; bb[q] = Eb[q]; pp[q] = Ep[q]; }
    } else {
        const int prev = (j - 1) * BC + b * C;
        f4 la = ((const f4*)(sa + prev))[tid];
        f4 lb = ((const f4*)(sb + prev))[tid];
        f4 lp = ((const f4*)(sp + prev))[tid];
        const float steps = (float)(i * LL);
        #pragma unroll
        for (int q = 0; q < 4; ++q) {
            float a = Ea[q], bq = Eb[q], p = Ep[q];
            wkv_combine(a, bq, p, wc[q] * steps, la[q], lb[q], lp[q]);
            aa[q] = a; bb[q] = bq; pp[q] = p;
        }
    }

    #pragma unroll
    for (int t = 0; t < LL; ++t) {
        f4 yo;
        #pragma unroll
        for (int q = 0; q < 4; ++q) {
            float kt = kb[t][q], vt = vb[t][q];
            yo[q] = wkv_ostep(aa[q], bb[q], pp[q], uc[q], kt, vt);
            wkv_step(aa[q], bb[q], pp[q], wc[q], kt, vt);
        }
        __builtin_nontemporal_store(yo, yp + t * C4);
    }
}

// ---------------------------------------------------------------------------
extern "C" void kernel_launch(void* const* d_in, const int* in_sizes, int n_in,
                              void* d_out, int out_size, void* d_ws, size_t ws_size,
                              hipStream_t stream) {
    // inputs: 0=B 1=T 2=C 3=w 4=u 5=k 6=v
    const float* w = (const float*)d_in[3];
    const float* u = (const float*)d_in[4];
    const float* k = (const float*)d_in[5];
    const float* v = (const float*)d_in[6];
    float* y = (float*)d_out;

    const int C  = in_sizes[3];          // 768
    const int BT = in_sizes[5] / C;      // B*T
    const int T  = 4096;                 // fixed problem instance (T = NCC*LL)
    const int B  = BT / T;               // 8

    const int BC = B * C;
    const size_t total = (size_t)BC * NCC;
    float* sa = (float*)d_ws;
    float* sb = sa + total;
    float* sp = sb + total;

    wkv_pass1<<<B * NCC, C / 4, 0, stream>>>(w, k, v, sa, sb, sp, B, T, C);

    const int n2 = BC * NSC;
    wkv_scan_local<<<(n2 + 255) / 256, 256, 0, stream>>>(w, sa, sb, sp, B, C);
    wkv_scan_super<<<(BC + 255) / 256, 256, 0, stream>>>(w, sa, sb, sp, B, C);

    wkv_pass3<<<B * NCC, C / 4, 0, stream>>>(w, u, k, v, sa, sb, sp, y, B, T, C);
}